// Round 5
// baseline (1032.010 us; speedup 1.0000x reference)
//
#include <hip/hip_runtime.h>
#include <hip/hip_bf16.h>
#include <math.h>

// ---------------------------------------------------------------------------
// 5x conv4d(valid)+relu -> flatten -> dense(1280->33)+relu -> dense(33->2)
// -> softmax.  B=256.
//
// R5: R4 + __launch_bounds__(NT, 4) on the cm kernels.
//  R4 post-mortem: conv2 reported VGPR_Count=52 while the kernel's essential
//  live state (acc[3][12]+wd[8]+od[7]) is 51 floats -> the compiler's
//  occupancy heuristic (1-arg launch_bounds) evicted acc from addressable
//  VGPRs (AGPR spill; v_dot2 can't source AGPRs -> 2 v_accvgpr moves per
//  dot2 = 3x VALU inflation; conv2 375us vs ~104us dot2-issue floor).
//  min-waves=4 -> VGPR cap 128 >> ~85 worst-case need -> acc stays in VGPRs.
//  - conv1-3 ("cm"): thread = (ox,oy) line, accumulates ALL COUT channels.
//    Row LDS reads amortize xCOUT; weights wave-uniform f16 global (s_load),
//    pre-packed by pack_weights (layout [ci][kw][kx][ky][co][4], kz padded).
//  - conv4/5 keep the R3 path (per-(co,ox,oy) lines, LDS weights).
//  - LDS slab per (b,ow) block, f16, z-stride ZP=24.
//  - kz pairs via v_dot2_f32_f16; odd-parity pairs via v_perm_b32.
// ---------------------------------------------------------------------------

#define BATCH 256
typedef _Float16 half_t;
typedef _Float16 h2_t __attribute__((ext_vector_type(2)));
typedef unsigned int uint32;

__device__ __forceinline__ float dot2f(uint32 a, uint32 b, float c) {
    return __builtin_amdgcn_fdot2(__builtin_bit_cast(h2_t, a),
                                  __builtin_bit_cast(h2_t, b), c, false);
}

// ---- weight pre-pack: fp32 global -> f16 global, [ci][kw][kx][ky][co][KP=4]
template <int CIN, int COUT, int K>
__device__ void pack_one(const float* __restrict__ w, half_t* __restrict__ wq,
                         int tid, int nt) {
    constexpr int KP = 4;
    constexpr int WTOT = CIN * K * K * K * COUT * KP;
    for (int t = tid; t < WTOT; t += nt) {
        const int kz = t % KP; int c = t / KP;
        const int co = c % COUT; c /= COUT;
        const int ky = c % K; c /= K;
        const int kx = c % K; c /= K;
        const int kw = c % K; const int ci = c / K;
        const float v = (kz < K)
            ? w[((((co * CIN + ci) * K + kw) * K + kx) * K + ky) * K + kz]
            : 0.0f;
        wq[t] = (half_t)v;
    }
}

__global__ void pack_weights(const float* __restrict__ w1,
                             const float* __restrict__ w2,
                             const float* __restrict__ w3,
                             half_t* __restrict__ q1,
                             half_t* __restrict__ q2,
                             half_t* __restrict__ q3) {
    pack_one<1, 3, 4>(w1, q1, threadIdx.x, blockDim.x);
    pack_one<3, 3, 4>(w2, q2, threadIdx.x, blockDim.x);
    pack_one<3, 4, 4>(w3, q3, threadIdx.x, blockDim.x);
}

// ---------------------------------------------------------------------------
// Co-merged conv: thread = (ox,oy), acc[COUT][OSZ]. Weights from f16 global
// at wave-uniform addresses (s_load). Used for conv1-3.
// MINW: min waves/EU for __launch_bounds__ -> VGPR budget 512/MINW.
// ---------------------------------------------------------------------------
template <int CIN, int COUT, int K, int ISZ, int OSZ,
          int IPG, int OPG, int ZP, int NT, bool INF32, int MINW>
__global__ __launch_bounds__(NT, MINW)
void conv4d_relu_cm(const void* __restrict__ in_v,
                    const half_t* __restrict__ wq,
                    const float* __restrict__ bias,
                    half_t* __restrict__ out) {
    constexpr int KP  = 4;                    // padded kz extent
    constexpr int R2  = ISZ * ISZ;
    constexpr int LINES = OSZ * OSZ;          // (ox,oy) lines per slab
    constexpr int RL  = OSZ + KP - 1;         // row halfs consumed
    constexpr int RQ  = (RL + 7) / 8;         // uint4 (8 f16) loads per row
    constexpr int NW  = RQ * 4;               // 32-bit words per row
    constexpr int NODD = (OSZ + 2) / 2;       // odd-parity pairs needed

    static_assert(NT >= LINES, "one compute pass requires NT >= LINES");
    static_assert(8 * RQ <= ZP, "row read overruns z-pad");
    static_assert(NODD + 1 <= NW, "perm source word out of range");

    __shared__ half_t slab[CIN * R2 * ZP];

    const int tid = threadIdx.x;
    const int b   = blockIdx.x / OSZ;
    const int ow  = blockIdx.x % OSZ;
    const int ox  = tid / OSZ;
    const int oy  = tid % OSZ;

    float acc[COUT][OSZ];
    #pragma unroll
    for (int co = 0; co < COUT; ++co) {
        const float bv = bias[co];
        #pragma unroll
        for (int oz = 0; oz < OSZ; ++oz) acc[co][oz] = bv;
    }

    for (int kw = 0; kw < K; ++kw) {
        __syncthreads();                      // readers of previous slab done
        const int iw = ow + kw;
        if constexpr (INF32) {
            // conv1: fp32 natural layout, CIN==1; float2 -> h2 packed stores
            const float* g = (const float*)in_v +
                ((size_t)b * ISZ + iw) * (size_t)(R2 * ISZ);
            for (int t = tid; t < (R2 * ISZ) / 2; t += NT) {
                const float2 v = ((const float2*)g)[t];
                const int e = 2 * t;
                const int r = e / ISZ, z = e % ISZ;   // ISZ even: no row split
                h2_t pv = { (half_t)v.x, (half_t)v.y };
                *(uint32*)&slab[r * ZP + z] = __builtin_bit_cast(uint32, pv);
            }
        } else {
            constexpr int CPR = IPG / 8;      // uint4 chunks per row
            constexpr int NCH = CIN * R2 * CPR;
            const half_t* inp = (const half_t*)in_v;
            for (int t = tid; t < NCH; t += NT) {
                const int ci  = t / (R2 * CPR);
                const int rem = t % (R2 * CPR);
                const int r = rem / CPR, c = rem % CPR;
                const uint4* g = (const uint4*)(inp +
                    ((size_t)(b * CIN + ci) * ISZ + iw) * (size_t)(R2 * IPG));
                const uint4 v = g[rem];       // == (r*IPG + 8c)/8
                *(uint4*)&slab[(ci * R2 + r) * ZP + 8 * c] = v;
            }
        }
        __syncthreads();

        if (tid < LINES) {
            #pragma unroll 1
            for (int ci = 0; ci < CIN; ++ci) {
                #pragma unroll 1
                for (int kx = 0; kx < K; ++kx) {
                    #pragma unroll
                    for (int ky = 0; ky < K; ++ky) {
                        const half_t* rp =
                            &slab[((ci * ISZ + ox + kx) * ISZ + oy + ky) * ZP];
                        uint32 wd[NW];
                        #pragma unroll
                        for (int q = 0; q < RQ; ++q) {
                            const uint4 v = ((const uint4*)rp)[q];
                            wd[4*q+0] = v.x; wd[4*q+1] = v.y;
                            wd[4*q+2] = v.z; wd[4*q+3] = v.w;
                        }
                        uint32 od[NODD];
                        #pragma unroll
                        for (int i = 0; i < NODD; ++i)
                            od[i] = __builtin_amdgcn_perm(wd[i + 1], wd[i],
                                                          0x05040302u);
                        // wave-uniform weight base -> scalar loads
                        const half_t* wp = wq +
                            ((((ci * K + kw) * K + kx) * K + ky) * COUT) * KP;
                        #pragma unroll
                        for (int co = 0; co < COUT; ++co) {
                            const uint2 wv = *(const uint2*)&wp[co * KP];
                            #pragma unroll
                            for (int oz = 0; oz < OSZ; ++oz) {
                                const int s1 = oz + 2;
                                const uint32 p0 = (oz & 1) ? od[oz >> 1]
                                                           : wd[oz >> 1];
                                const uint32 p1 = (s1 & 1) ? od[s1 >> 1]
                                                           : wd[s1 >> 1];
                                acc[co][oz] = dot2f(p0, wv.x,
                                               dot2f(p1, wv.y, acc[co][oz]));
                            }
                        }
                    }
                }
            }
        }
    }

    // ---- epilogue: relu, pack, store to [b][co][ow][ox][oy][OPG]
    if (tid < LINES) {
        #pragma unroll
        for (int co = 0; co < COUT; ++co) {
            half_t* op = out +
                (((((size_t)b * COUT + co) * OSZ + ow) * OSZ + ox) * OSZ + oy)
                * OPG;
            #pragma unroll
            for (int p = 0; p < OSZ / 2; ++p) {
                h2_t pv = { (half_t)fmaxf(acc[co][2*p],     0.0f),
                            (half_t)fmaxf(acc[co][2*p + 1], 0.0f) };
                ((uint32*)op)[p] = __builtin_bit_cast(uint32, pv);
            }
            if constexpr (OSZ & 1)
                op[OSZ - 1] = (half_t)fmaxf(acc[co][OSZ - 1], 0.0f);
        }
    }
}

// ---------------------------------------------------------------------------
// R3 conv path (per-(co,ox,oy) lines, LDS weights) — kept for conv4/conv5.
// ---------------------------------------------------------------------------
template <int CIN, int COUT, int K, int ISZ, int OSZ,
          int IPG, int OPG, int ZP, int NT, bool INF32>
__global__ __launch_bounds__(NT)
void conv4d_relu_f16(const void* __restrict__ in_v,
                     const float* __restrict__ w,
                     const float* __restrict__ bias,
                     half_t* __restrict__ out) {
    constexpr int KP  = 4;
    constexpr int R2  = ISZ * ISZ;
    constexpr int WTOT = CIN * K * K * K * COUT * KP;
    constexpr int LINES = COUT * OSZ * OSZ;
    constexpr int NIT = (LINES + NT - 1) / NT;
    constexpr int RL  = OSZ + KP - 1;
    constexpr int RQ  = (RL + 7) / 8;
    constexpr int NW  = RQ * 4;
    constexpr int NODD = (OSZ + 2) / 2;

    static_assert(8 * RQ <= ZP, "row read overruns z-pad");
    static_assert(NODD + 1 <= NW, "perm source word out of range");

    __shared__ half_t sw[WTOT];
    __shared__ half_t slab[CIN * R2 * ZP];

    const int tid = threadIdx.x;
    const int b   = blockIdx.x / OSZ;
    const int ow  = blockIdx.x % OSZ;

    for (int t = tid; t < WTOT; t += NT) {
        const int kz = t % KP; int c = t / KP;
        const int co = c % COUT; c /= COUT;
        const int ky = c % K; c /= K;
        const int kx = c % K; c /= K;
        const int kw = c % K; const int ci = c / K;
        const float v = (kz < K)
            ? w[((((co * CIN + ci) * K + kw) * K + kx) * K + ky) * K + kz]
            : 0.0f;
        sw[t] = (half_t)v;
    }

    float acc[NIT][OSZ];
    #pragma unroll
    for (int it = 0; it < NIT; ++it) {
        const int line = tid + it * NT;
        const float bv = (line < LINES) ? bias[line % COUT] : 0.0f;
        #pragma unroll
        for (int oz = 0; oz < OSZ; ++oz) acc[it][oz] = bv;
    }

    for (int kw = 0; kw < K; ++kw) {
        __syncthreads();
        const int iw = ow + kw;
        if constexpr (INF32) {
            const float* g = (const float*)in_v + ((size_t)b * ISZ + iw) * (size_t)(R2 * ISZ);
            for (int t = tid; t < R2 * ISZ; t += NT) {
                const int r = t / ISZ, z = t % ISZ;
                slab[r * ZP + z] = (half_t)g[t];
            }
        } else {
            constexpr int CPR = IPG / 8;
            constexpr int NCH = CIN * R2 * CPR;
            const half_t* inp = (const half_t*)in_v;
            for (int t = tid; t < NCH; t += NT) {
                const int ci  = t / (R2 * CPR);
                const int rem = t % (R2 * CPR);
                const int r = rem / CPR, c = rem % CPR;
                const uint4* g = (const uint4*)(inp +
                    ((size_t)(b * CIN + ci) * ISZ + iw) * (size_t)(R2 * IPG));
                const uint4 v = g[rem];
                *(uint4*)&slab[(ci * R2 + r) * ZP + 8 * c] = v;
            }
        }
        __syncthreads();

        #pragma unroll
        for (int it = 0; it < NIT; ++it) {
            const int line = tid + it * NT;
            if (line >= LINES) continue;
            const int co = line % COUT;
            const int xy = line / COUT;
            const int ox = xy / OSZ;
            const int oy = xy % OSZ;
            #pragma unroll 1
            for (int ci = 0; ci < CIN; ++ci) {
                #pragma unroll 1
                for (int kx = 0; kx < K; ++kx) {
                    #pragma unroll
                    for (int ky = 0; ky < K; ++ky) {
                        const half_t* rp = &slab[((ci * ISZ + ox + kx) * ISZ + oy + ky) * ZP];
                        uint32 wd[NW];
                        #pragma unroll
                        for (int q = 0; q < RQ; ++q) {
                            const uint4 v = ((const uint4*)rp)[q];
                            wd[4*q+0] = v.x; wd[4*q+1] = v.y;
                            wd[4*q+2] = v.z; wd[4*q+3] = v.w;
                        }
                        uint32 od[NODD];
                        #pragma unroll
                        for (int i = 0; i < NODD; ++i)
                            od[i] = __builtin_amdgcn_perm(wd[i + 1], wd[i], 0x05040302u);
                        const int wb = ((((ci * K + kw) * K + kx) * K + ky) * COUT + co) * KP;
                        const uint2 wv = *(const uint2*)&sw[wb];
                        #pragma unroll
                        for (int oz = 0; oz < OSZ; ++oz) {
                            const int s1 = oz + 2;
                            const uint32 p0 = (oz & 1) ? od[oz >> 1] : wd[oz >> 1];
                            const uint32 p1 = (s1 & 1) ? od[s1 >> 1] : wd[s1 >> 1];
                            acc[it][oz] = dot2f(p0, wv.x, dot2f(p1, wv.y, acc[it][oz]));
                        }
                    }
                }
            }
        }
    }

    #pragma unroll
    for (int it = 0; it < NIT; ++it) {
        const int line = tid + it * NT;
        if (line >= LINES) continue;
        const int co = line % COUT;
        const int xy = line / COUT;
        const int ox = xy / OSZ;
        const int oy = xy % OSZ;
        half_t* op = out + (((((size_t)b * COUT + co) * OSZ + ow) * OSZ + ox) * OSZ + oy) * OPG;
        #pragma unroll
        for (int p = 0; p < OSZ / 2; ++p) {
            h2_t pv = { (half_t)fmaxf(acc[it][2*p],     0.0f),
                        (half_t)fmaxf(acc[it][2*p + 1], 0.0f) };
            ((uint32*)op)[p] = __builtin_bit_cast(uint32, pv);
        }
        if constexpr (OSZ & 1)
            op[OSZ - 1] = (half_t)fmaxf(acc[it][OSZ - 1], 0.0f);
    }
}

// dense1: out[b,j] = relu(sum_k h[b,k]*w[j,k] + bias[j]); h f16 [256,1280]
__global__ void dense1_relu_f16(const half_t* __restrict__ h,
                                const float* __restrict__ w,
                                const float* __restrict__ bias,
                                float* __restrict__ out) {
    int idx = blockIdx.x * blockDim.x + threadIdx.x;
    if (idx >= BATCH * 33) return;
    const int j = idx % 33;
    const int i = idx / 33;
    const half_t* hr = h + (size_t)i * 1280;
    const float*  wr = w + (size_t)j * 1280;
    float a0 = bias[j], a1 = 0.f, a2 = 0.f, a3 = 0.f;
    for (int k = 0; k < 1280; k += 4) {
        a0 = fmaf((float)hr[k + 0], wr[k + 0], a0);
        a1 = fmaf((float)hr[k + 1], wr[k + 1], a1);
        a2 = fmaf((float)hr[k + 2], wr[k + 2], a2);
        a3 = fmaf((float)hr[k + 3], wr[k + 3], a3);
    }
    out[idx] = fmaxf((a0 + a1) + (a2 + a3), 0.0f);
}

// dense2 + softmax over 2 classes. h:[256,33] fp32, w:[2,33], out:[256,2]
__global__ void dense2_softmax(const float* __restrict__ h,
                               const float* __restrict__ w,
                               const float* __restrict__ bias,
                               float* __restrict__ out) {
    int i = blockIdx.x * blockDim.x + threadIdx.x;
    if (i >= BATCH) return;
    const float* hr = h + (size_t)i * 33;
    float a0 = bias[0], a1 = bias[1];
    for (int k = 0; k < 33; ++k) {
        a0 = fmaf(hr[k], w[k], a0);
        a1 = fmaf(hr[k], w[33 + k], a1);
    }
    const float m = fmaxf(a0, a1);
    const float e0 = expf(a0 - m);
    const float e1 = expf(a1 - m);
    const float s = e0 + e1;
    out[i * 2 + 0] = e0 / s;
    out[i * 2 + 1] = e1 / s;
}

extern "C" void kernel_launch(void* const* d_in, const int* in_sizes, int n_in,
                              void* d_out, int out_size, void* d_ws, size_t ws_size,
                              hipStream_t stream) {
    const float* x   = (const float*)d_in[0];
    const float* w1  = (const float*)d_in[1];
    const float* b1  = (const float*)d_in[2];
    const float* w2  = (const float*)d_in[3];
    const float* b2  = (const float*)d_in[4];
    const float* w3  = (const float*)d_in[5];
    const float* b3  = (const float*)d_in[6];
    const float* w4  = (const float*)d_in[7];
    const float* b4  = (const float*)d_in[8];
    const float* w5  = (const float*)d_in[9];
    const float* b5  = (const float*)d_in[10];
    const float* dw1 = (const float*)d_in[11];
    const float* db1 = (const float*)d_in[12];
    const float* dw2 = (const float*)d_in[13];
    const float* db2 = (const float*)d_in[14];

    // Workspace (f16 units). Region A at 0, region B at 42M f16 (84 MB).
    //  A: h1 [256][3][15][15][15][16] = 41.472M f16  / h3 / h5
    //     + packed f16 weights q1..q3 at A+41.6M (14K f16, above h1 end)
    //  B: h2 [256][3][12][12][12][16] = 21.23M f16  / h4 / h6(fp32, +8M)
    half_t* wsA = (half_t*)d_ws;
    half_t* wsB = wsA + 42000000;

    half_t* h1 = wsA;                 // padded z=16
    half_t* h2 = wsB;                 // padded z=16
    half_t* h3 = wsA;                 // padded z=16
    half_t* h4 = wsB;                 // padded z=8
    half_t* h5 = wsA;                 // natural [256][1280]
    float*  h6 = (float*)(wsB + 8000000);
    half_t* q1 = wsA + 41600000;      // 1*64*3*4 = 768 f16
    half_t* q2 = q1 + 768;            // 3*64*3*4 = 2304 f16
    half_t* q3 = q2 + 2304;           // 3*64*4*4 = 3072 f16
    float* outp = (float*)d_out;

    // weight pre-pack for conv1-3 (tiny; stream-ordered before convs)
    hipLaunchKernelGGL(pack_weights, dim3(1), dim3(256), 0, stream,
                       w1, w2, w3, q1, q2, q3);

    // conv1: in fp32 natural -> h1;  blocks (b,ow)=3840, 225 lines/block
    hipLaunchKernelGGL((conv4d_relu_cm<1, 3, 4, 18, 15, 8, 16, 24, 256, true, 4>),
                       dim3(BATCH * 15), dim3(256), 0, stream, x, q1, b1, h1);
    // conv2: h1 -> h2;  3072 blocks, 144 lines/block
    hipLaunchKernelGGL((conv4d_relu_cm<3, 3, 4, 15, 12, 16, 16, 24, 192, false, 4>),
                       dim3(BATCH * 12), dim3(192), 0, stream, h1, q2, b2, h2);
    // conv3: h2 -> h3;  2304 blocks, 81 lines/block
    hipLaunchKernelGGL((conv4d_relu_cm<3, 4, 4, 12, 9, 16, 16, 24, 128, false, 4>),
                       dim3(BATCH * 9), dim3(128), 0, stream, h2, q3, b3, h3);
    // conv4: h3 -> h4;  1536 blocks (R3 path)
    hipLaunchKernelGGL((conv4d_relu_f16<4, 5, 4, 9, 6, 16, 8, 24, 192, false>),
                       dim3(BATCH * 6), dim3(192), 0, stream, h3, w4, b4, h4);
    // conv5: h4 -> h5 (natural, z=4);  1024 blocks (R3 path)
    hipLaunchKernelGGL((conv4d_relu_f16<5, 5, 3, 6, 4, 8, 4, 8, 128, false>),
                       dim3(BATCH * 4), dim3(128), 0, stream, h4, w5, b5, h5);
    {   // dense1
        dim3 grid((BATCH * 33 + 255) / 256);
        hipLaunchKernelGGL(dense1_relu_f16, grid, dim3(256), 0, stream, h5, dw1, db1, h6);
    }
    {   // dense2 + softmax
        hipLaunchKernelGGL(dense2_softmax, dim3(1), dim3(256), 0, stream,
                           h6, dw2, db2, outp);
    }
}

// Round 7
// 787.763 us; speedup vs baseline: 1.3101x; 1.3101x over previous
//
#include <hip/hip_runtime.h>
#include <hip/hip_bf16.h>
#include <math.h>

// ---------------------------------------------------------------------------
// 5x conv4d(valid)+relu -> flatten -> dense(1280->33)+relu -> dense(33->2)
// -> softmax.  B=256.
//
// R7: conv1-3 banded-GEMM on MFMA, switched f16 -> bf16.
//  R6 post-mortem: formulation re-derived correct at concrete points under
//  the assumed MFMA layout model; every HW-verified layout fact (m89/m92/m97
//  refchecked) is for the bf16 instruction -- the f16 sibling's operand
//  layout was never correctness-verified and is the prime suspect. R7 uses
//  __builtin_amdgcn_mfma_f32_16x16x32_bf16 (short8 operands, f32x4 acc):
//    M = (ox,oy), N = co*16+oz, K = (ci,kx,ky)x(iz padded to ZPK), acc kw.
//    B[k][n] = w[co][ci,kx,ky][iz-oz] (banded, 0 outside) pre-packed in
//      fragment order [kw][ks][nt][lane][8] (bf16, RNE).
//    A[m][k] = slab row (ci*R2+(ox+kx)*ISZ+(oy+ky)), 8 contiguous iz ->
//      ONE ds_read_b128 per fragment.  Same (lane,half)->k formula both
//      sides -> contraction correct for any internal k-slot order.
//    D: col=lane&15 (=oz), row=(lane>>4)*4+reg (=m)  [m89-verified].
//  h1,h2 stored bf16 (staging = raw bit-copies); conv3 epilogue emits f16
//  h3 so conv4/5 keep the verified R3 dot2-f16 path. Slab fully zero-inited
//  (NaN hardening for ZPK>ISZ pads + OOB margin). dense1/2 unchanged.
// ---------------------------------------------------------------------------

#define BATCH 256
typedef _Float16 half_t;
typedef _Float16 h2_t  __attribute__((ext_vector_type(2)));
typedef short    bf16x8 __attribute__((ext_vector_type(8)));
typedef float    f32x4 __attribute__((ext_vector_type(4)));
typedef unsigned int   uint32;
typedef unsigned short ushort16;

__device__ __forceinline__ float dot2f(uint32 a, uint32 b, float c) {
    return __builtin_amdgcn_fdot2(__builtin_bit_cast(h2_t, a),
                                  __builtin_bit_cast(h2_t, b), c, false);
}

// f32 -> bf16 bits, round-to-nearest-even (finite inputs only)
__device__ __forceinline__ ushort16 f2bf(float f) {
    const uint32 u = __builtin_bit_cast(uint32, f);
    return (ushort16)((u + 0x7FFFu + ((u >> 16) & 1u)) >> 16);
}

// ---- B-matrix pre-pack: fragment order [kw][ks][nt][lane][8], bf16 -------
template <int CIN, int COUT, int ISZ, int OSZ, int ZPK, int KS>
__device__ void pack_mfma_one(const float* __restrict__ w,
                              ushort16* __restrict__ Bq, int gtid, int gstride) {
    constexpr int TOT = 4 * KS * COUT * 512;   // 512 bf16 per fragment
    for (int t = gtid; t < TOT; t += gstride) {
        const int h  = t & 7;
        const int l  = (t >> 3) & 63;
        const int f  = t >> 9;                 // (kw*KS+ks)*COUT + nt
        const int nt = f % COUT;
        const int ks = (f / COUT) % KS;
        const int kw = f / (COUT * KS);
        const int k  = ks * 32 + (l >> 4) * 8 + h;
        const int combo = k / ZPK;
        const int iz = k - combo * ZPK;
        const int ci = combo >> 4;             // combo = (ci*4+kx)*4+ky
        const int kx = (combo >> 2) & 3;
        const int ky = combo & 3;
        const int oz = l & 15;
        const int kz = iz - oz;
        ushort16 v = 0;
        if (oz < OSZ && kz >= 0 && kz < 4 && iz < ISZ)
            v = f2bf(w[((((nt * CIN + ci) * 4 + kw) * 4 + kx) * 4 + ky) * 4 + kz]);
        Bq[t] = v;
    }
}

__global__ void pack_weights_mfma(const float* __restrict__ w1,
                                  const float* __restrict__ w2,
                                  const float* __restrict__ w3,
                                  ushort16* __restrict__ Bq1,
                                  ushort16* __restrict__ Bq2,
                                  ushort16* __restrict__ Bq3) {
    const int gtid = blockIdx.x * blockDim.x + threadIdx.x;
    const int gs   = gridDim.x * blockDim.x;
    pack_mfma_one<1, 3, 18, 15, 24, 12>(w1, Bq1, gtid, gs);
    pack_mfma_one<3, 3, 15, 12, 16, 24>(w2, Bq2, gtid, gs);
    pack_mfma_one<3, 4, 12,  9, 16, 24>(w3, Bq3, gtid, gs);
}

// ---------------------------------------------------------------------------
// MFMA conv (bf16): one (b,ow) slab per block; waves split M-tiles; each wave
// accumulates all COUT n-tiles. OUTF16: emit f16 bits (for conv3->conv4).
// ---------------------------------------------------------------------------
template <int CIN, int COUT, int ISZ, int OSZ, int ZPK, int KS,
          int MT_TOT, int NT, bool INF32, bool OUTF16>
__global__ __launch_bounds__(NT)
void conv4d_mfma(const void* __restrict__ in_v,
                 const ushort16* __restrict__ Bq,
                 const float* __restrict__ bias,
                 ushort16* __restrict__ out) {
    constexpr int K   = 4;
    constexpr int R2  = ISZ * ISZ;
    constexpr int NW  = NT / 64;
    constexpr int MT_PER = (MT_TOT + NW - 1) / NW;
    constexpr int SLAB = (CIN * R2 + 24) * ZPK;  // +24 rows OOB margin
    static_assert(CIN * 16 * ZPK == KS * 32, "K-dim bookkeeping");
    static_assert(ZPK % 8 == 0, "8-slice must not straddle combos");

    __shared__ ushort16 slab[SLAB];

    const int tid = threadIdx.x;
    const int l   = tid & 63;
    const int wv  = tid >> 6;
    const int b   = blockIdx.x / OSZ;
    const int ow  = blockIdx.x % OSZ;
    const int lg  = l >> 4;

    // NaN hardening: pads (ZPK>ISZ) and OOB margin must be finite.
    for (int t = tid; t < SLAB; t += NT) slab[t] = 0;

    // per-lane A-row base per owned M-tile
    int mbase[MT_PER];
    #pragma unroll
    for (int i = 0; i < MT_PER; ++i) {
        const int mt = wv + NW * i;
        const int m  = (mt < MT_TOT) ? (mt * 16 + (l & 15)) : 0;
        mbase[i] = (m / OSZ) * ISZ + (m % OSZ);
    }

    f32x4 acc[MT_PER][COUT];
    #pragma unroll
    for (int i = 0; i < MT_PER; ++i)
        #pragma unroll
        for (int nt = 0; nt < COUT; ++nt)
            acc[i][nt] = (f32x4){0.f, 0.f, 0.f, 0.f};

    for (int kw = 0; kw < K; ++kw) {
        __syncthreads();                       // readers of previous slab done
        const int iw = ow + kw;
        if constexpr (INF32) {
            // conv1: fp32 natural, CIN==1; float2 -> packed bf16 pairs
            const float* g = (const float*)in_v +
                ((size_t)b * ISZ + iw) * (size_t)(R2 * ISZ);
            for (int t = tid; t < (R2 * ISZ) / 2; t += NT) {
                const float2 v = ((const float2*)g)[t];
                const int e = 2 * t;
                const int r = e / ISZ, z = e % ISZ;    // ISZ even: no straddle
                const uint32 pv = (uint32)f2bf(v.x) | ((uint32)f2bf(v.y) << 16);
                *(uint32*)&slab[r * ZPK + z] = pv;
            }
        } else {
            constexpr int CPR = 2;             // 16 elems per row = 2 uint4
            constexpr int NCH = CIN * R2 * CPR;
            const ushort16* inp = (const ushort16*)in_v;
            for (int t = tid; t < NCH; t += NT) {
                const int ci  = t / (R2 * CPR);
                const int rem = t % (R2 * CPR);
                const uint4* g = (const uint4*)(inp +
                    ((size_t)(b * CIN + ci) * ISZ + iw) * (size_t)(R2 * 16));
                const uint4 v = g[rem];
                *(uint4*)&slab[(ci * R2) * ZPK + rem * 8] = v;  // ZPK==16 here
            }
        }
        __syncthreads();

        #pragma unroll 2
        for (int ks = 0; ks < KS; ++ks) {
            // weight fragments (L2-resident, coalesced 1KB per fragment)
            bf16x8 bq[COUT];
            const ushort16* bp = Bq + (size_t)((kw * KS + ks) * COUT) * 512 + l * 8;
            #pragma unroll
            for (int nt = 0; nt < COUT; ++nt)
                bq[nt] = *(const bf16x8*)(bp + nt * 512);
            // A fragment address parts (per-lane)
            const int k8    = ks * 32 + lg * 8;
            const int combo = k8 / ZPK;
            const int iz0   = k8 - combo * ZPK;
            const int ci    = combo >> 4;
            const int kx    = (combo >> 2) & 3;
            const int ky    = combo & 3;
            const int roff  = ci * R2 + kx * ISZ + ky;
            #pragma unroll
            for (int i = 0; i < MT_PER; ++i) {
                if (wv + NW * i < MT_TOT) {
                    const bf16x8 a =
                        *(const bf16x8*)&slab[(mbase[i] + roff) * ZPK + iz0];
                    #pragma unroll
                    for (int nt = 0; nt < COUT; ++nt)
                        acc[i][nt] = __builtin_amdgcn_mfma_f32_16x16x32_bf16(
                            a, bq[nt], acc[i][nt], 0, 0, 0);
                }
            }
        }
    }

    // ---- epilogue: D col = lane&15 (= oz), row = (lane>>4)*4 + reg (= m)
    const int oz = l & 15;
    #pragma unroll
    for (int i = 0; i < MT_PER; ++i) {
        const int mt = wv + NW * i;
        if (mt < MT_TOT) {
            #pragma unroll
            for (int nt = 0; nt < COUT; ++nt) {
                const float bv = bias[nt];
                #pragma unroll
                for (int r = 0; r < 4; ++r) {
                    const int m = mt * 16 + (l >> 4) * 4 + r;
                    if (m < OSZ * OSZ) {
                        const int ox = m / OSZ, oy = m % OSZ;
                        const float vv = fmaxf(acc[i][nt][r] + bv, 0.f);
                        ushort16 bits;
                        if constexpr (OUTF16) {
                            const half_t hv = (half_t)vv;
                            bits = __builtin_bit_cast(ushort16, hv);
                        } else {
                            bits = f2bf(vv);
                        }
                        out[(((((size_t)b * COUT + nt) * OSZ + ow) * OSZ + ox)
                             * OSZ + oy) * 16 + oz] = bits;
                    }
                }
            }
        }
    }
}

// ---------------------------------------------------------------------------
// R3 conv path (per-(co,ox,oy) lines, LDS weights, f16 dot2) — conv4/conv5.
// ---------------------------------------------------------------------------
template <int CIN, int COUT, int K, int ISZ, int OSZ,
          int IPG, int OPG, int ZP, int NT, bool INF32>
__global__ __launch_bounds__(NT)
void conv4d_relu_f16(const void* __restrict__ in_v,
                     const float* __restrict__ w,
                     const float* __restrict__ bias,
                     half_t* __restrict__ out) {
    constexpr int KP  = 4;
    constexpr int R2  = ISZ * ISZ;
    constexpr int WTOT = CIN * K * K * K * COUT * KP;
    constexpr int LINES = COUT * OSZ * OSZ;
    constexpr int NIT = (LINES + NT - 1) / NT;
    constexpr int RL  = OSZ + KP - 1;
    constexpr int RQ  = (RL + 7) / 8;
    constexpr int NW  = RQ * 4;
    constexpr int NODD = (OSZ + 2) / 2;

    static_assert(8 * RQ <= ZP, "row read overruns z-pad");
    static_assert(NODD + 1 <= NW, "perm source word out of range");

    __shared__ half_t sw[WTOT];
    __shared__ half_t slab[CIN * R2 * ZP];

    const int tid = threadIdx.x;
    const int b   = blockIdx.x / OSZ;
    const int ow  = blockIdx.x % OSZ;

    for (int t = tid; t < WTOT; t += NT) {
        const int kz = t % KP; int c = t / KP;
        const int co = c % COUT; c /= COUT;
        const int ky = c % K; c /= K;
        const int kx = c % K; c /= K;
        const int kw = c % K; const int ci = c / K;
        const float v = (kz < K)
            ? w[((((co * CIN + ci) * K + kw) * K + kx) * K + ky) * K + kz]
            : 0.0f;
        sw[t] = (half_t)v;
    }

    float acc[NIT][OSZ];
    #pragma unroll
    for (int it = 0; it < NIT; ++it) {
        const int line = tid + it * NT;
        const float bv = (line < LINES) ? bias[line % COUT] : 0.0f;
        #pragma unroll
        for (int oz = 0; oz < OSZ; ++oz) acc[it][oz] = bv;
    }

    for (int kw = 0; kw < K; ++kw) {
        __syncthreads();
        const int iw = ow + kw;
        if constexpr (INF32) {
            const float* g = (const float*)in_v + ((size_t)b * ISZ + iw) * (size_t)(R2 * ISZ);
            for (int t = tid; t < R2 * ISZ; t += NT) {
                const int r = t / ISZ, z = t % ISZ;
                slab[r * ZP + z] = (half_t)g[t];
            }
        } else {
            constexpr int CPR = IPG / 8;
            constexpr int NCH = CIN * R2 * CPR;
            const half_t* inp = (const half_t*)in_v;
            for (int t = tid; t < NCH; t += NT) {
                const int ci  = t / (R2 * CPR);
                const int rem = t % (R2 * CPR);
                const int r = rem / CPR, c = rem % CPR;
                const uint4* g = (const uint4*)(inp +
                    ((size_t)(b * CIN + ci) * ISZ + iw) * (size_t)(R2 * IPG));
                const uint4 v = g[rem];
                *(uint4*)&slab[(ci * R2 + r) * ZP + 8 * c] = v;
            }
        }
        __syncthreads();

        #pragma unroll
        for (int it = 0; it < NIT; ++it) {
            const int line = tid + it * NT;
            if (line >= LINES) continue;
            const int co = line % COUT;
            const int xy = line / COUT;
            const int ox = xy / OSZ;
            const int oy = xy % OSZ;
            #pragma unroll 1
            for (int ci = 0; ci < CIN; ++ci) {
                #pragma unroll 1
                for (int kx = 0; kx < K; ++kx) {
                    #pragma unroll
                    for (int ky = 0; ky < K; ++ky) {
                        const half_t* rp = &slab[((ci * ISZ + ox + kx) * ISZ + oy + ky) * ZP];
                        uint32 wd[NW];
                        #pragma unroll
                        for (int q = 0; q < RQ; ++q) {
                            const uint4 v = ((const uint4*)rp)[q];
                            wd[4*q+0] = v.x; wd[4*q+1] = v.y;
                            wd[4*q+2] = v.z; wd[4*q+3] = v.w;
                        }
                        uint32 od[NODD];
                        #pragma unroll
                        for (int i = 0; i < NODD; ++i)
                            od[i] = __builtin_amdgcn_perm(wd[i + 1], wd[i], 0x05040302u);
                        const int wb = ((((ci * K + kw) * K + kx) * K + ky) * COUT + co) * KP;
                        const uint2 wv = *(const uint2*)&sw[wb];
                        #pragma unroll
                        for (int oz = 0; oz < OSZ; ++oz) {
                            const int s1 = oz + 2;
                            const uint32 p0 = (oz & 1) ? od[oz >> 1] : wd[oz >> 1];
                            const uint32 p1 = (s1 & 1) ? od[s1 >> 1] : wd[s1 >> 1];
                            acc[it][oz] = dot2f(p0, wv.x, dot2f(p1, wv.y, acc[it][oz]));
                        }
                    }
                }
            }
        }
    }

    #pragma unroll
    for (int it = 0; it < NIT; ++it) {
        const int line = tid + it * NT;
        if (line >= LINES) continue;
        const int co = line % COUT;
        const int xy = line / COUT;
        const int ox = xy / OSZ;
        const int oy = xy % OSZ;
        half_t* op = out + (((((size_t)b * COUT + co) * OSZ + ow) * OSZ + ox) * OSZ + oy) * OPG;
        #pragma unroll
        for (int p = 0; p < OSZ / 2; ++p) {
            h2_t pv = { (half_t)fmaxf(acc[it][2*p],     0.0f),
                        (half_t)fmaxf(acc[it][2*p + 1], 0.0f) };
            ((uint32*)op)[p] = __builtin_bit_cast(uint32, pv);
        }
        if constexpr (OSZ & 1)
            op[OSZ - 1] = (half_t)fmaxf(acc[it][OSZ - 1], 0.0f);
    }
}

// dense1: out[b,j] = relu(sum_k h[b,k]*w[j,k] + bias[j]); h f16 [256,1280]
__global__ void dense1_relu_f16(const half_t* __restrict__ h,
                                const float* __restrict__ w,
                                const float* __restrict__ bias,
                                float* __restrict__ out) {
    int idx = blockIdx.x * blockDim.x + threadIdx.x;
    if (idx >= BATCH * 33) return;
    const int j = idx % 33;
    const int i = idx / 33;
    const half_t* hr = h + (size_t)i * 1280;
    const float*  wr = w + (size_t)j * 1280;
    float a0 = bias[j], a1 = 0.f, a2 = 0.f, a3 = 0.f;
    for (int k = 0; k < 1280; k += 4) {
        a0 = fmaf((float)hr[k + 0], wr[k + 0], a0);
        a1 = fmaf((float)hr[k + 1], wr[k + 1], a1);
        a2 = fmaf((float)hr[k + 2], wr[k + 2], a2);
        a3 = fmaf((float)hr[k + 3], wr[k + 3], a3);
    }
    out[idx] = fmaxf((a0 + a1) + (a2 + a3), 0.0f);
}

// dense2 + softmax over 2 classes. h:[256,33] fp32, w:[2,33], out:[256,2]
__global__ void dense2_softmax(const float* __restrict__ h,
                               const float* __restrict__ w,
                               const float* __restrict__ bias,
                               float* __restrict__ out) {
    int i = blockIdx.x * blockDim.x + threadIdx.x;
    if (i >= BATCH) return;
    const float* hr = h + (size_t)i * 33;
    float a0 = bias[0], a1 = bias[1];
    for (int k = 0; k < 33; ++k) {
        a0 = fmaf(hr[k], w[k], a0);
        a1 = fmaf(hr[k], w[33 + k], a1);
    }
    const float m = fmaxf(a0, a1);
    const float e0 = expf(a0 - m);
    const float e1 = expf(a1 - m);
    const float s = e0 + e1;
    out[i * 2 + 0] = e0 / s;
    out[i * 2 + 1] = e1 / s;
}

extern "C" void kernel_launch(void* const* d_in, const int* in_sizes, int n_in,
                              void* d_out, int out_size, void* d_ws, size_t ws_size,
                              hipStream_t stream) {
    const float* x   = (const float*)d_in[0];
    const float* w1  = (const float*)d_in[1];
    const float* b1  = (const float*)d_in[2];
    const float* w2  = (const float*)d_in[3];
    const float* b2  = (const float*)d_in[4];
    const float* w3  = (const float*)d_in[5];
    const float* b3  = (const float*)d_in[6];
    const float* w4  = (const float*)d_in[7];
    const float* b4  = (const float*)d_in[8];
    const float* w5  = (const float*)d_in[9];
    const float* b5  = (const float*)d_in[10];
    const float* dw1 = (const float*)d_in[11];
    const float* db1 = (const float*)d_in[12];
    const float* dw2 = (const float*)d_in[13];
    const float* db2 = (const float*)d_in[14];

    // Workspace (16-bit units). Region A at 0, region B at 42M (84 MB).
    //  A: h1 [256][3][15][15][15][16] bf16 = 41.472M  / h3(f16) / h5(f16)
    //     + MFMA weight fragments Bq1..Bq3 (bf16) at A+41.5M
    //  B: h2 [256][3][12][12][12][16] bf16 = 21.23M  / h4(f16) / h6(fp32,+8M)
    ushort16* wsA = (ushort16*)d_ws;
    ushort16* wsB = wsA + 42000000;

    ushort16* h1 = wsA;               // bf16, padded z=16
    ushort16* h2 = wsB;               // bf16, padded z=16
    ushort16* h3 = wsA;               // f16 bits, padded z=16
    half_t*   h4 = (half_t*)wsB;      // f16, padded z=8
    half_t*   h5 = (half_t*)wsA;      // f16, natural [256][1280]
    float*    h6 = (float*)(wsB + 8000000);
    ushort16* Bq1 = wsA + 41500000;   // 4*12*3*512 = 73,728
    ushort16* Bq2 = wsA + 41600000;   // 4*24*3*512 = 147,456
    ushort16* Bq3 = wsA + 41760000;   // 4*24*4*512 = 196,608
    float* outp = (float*)d_out;

    // weight fragment pre-pack for conv1-3
    hipLaunchKernelGGL(pack_weights_mfma, dim3(64), dim3(256), 0, stream,
                       w1, w2, w3, Bq1, Bq2, Bq3);

    // conv1: x fp32 -> h1 (bf16).  M=225 (15 Mt), ZPK=24, KS=12.
    hipLaunchKernelGGL((conv4d_mfma<1, 3, 18, 15, 24, 12, 15, 256, true, false>),
                       dim3(BATCH * 15), dim3(256), 0, stream, x, Bq1, b1, h1);
    // conv2: h1 -> h2 (bf16).  M=144 (9 Mt), ZPK=16, KS=24.
    hipLaunchKernelGGL((conv4d_mfma<3, 3, 15, 12, 16, 24, 9, 256, false, false>),
                       dim3(BATCH * 12), dim3(256), 0, stream, h1, Bq2, b2, h2);
    // conv3: h2 -> h3 (f16 out for conv4).  M=81 (6 Mt), ZPK=16, KS=24.
    hipLaunchKernelGGL((conv4d_mfma<3, 4, 12, 9, 16, 24, 6, 256, false, true>),
                       dim3(BATCH * 9), dim3(256), 0, stream, h2, Bq3, b3, h3);
    // conv4: h3 -> h4;  R3 f16 dot2 path
    hipLaunchKernelGGL((conv4d_relu_f16<4, 5, 4, 9, 6, 16, 8, 24, 192, false>),
                       dim3(BATCH * 6), dim3(192), 0, stream, h3, w4, b4, h4);
    // conv5: h4 -> h5 (natural, z=4);  R3 f16 dot2 path
    hipLaunchKernelGGL((conv4d_relu_f16<5, 5, 3, 6, 4, 8, 4, 8, 128, false>),
                       dim3(BATCH * 4), dim3(128), 0, stream, h4, w5, b5, h5);
    {   // dense1
        dim3 grid((BATCH * 33 + 255) / 256);
        hipLaunchKernelGGL(dense1_relu_f16, grid, dim3(256), 0, stream, h5, dw1, db1, h6);
    }
    {   // dense2 + softmax
        hipLaunchKernelGGL(dense2_softmax, dim3(1), dim3(256), 0, stream,
                           h6, dw2, db2, outp);
    }
}

// Round 8
// 759.419 us; speedup vs baseline: 1.3589x; 1.0373x over previous
//
#include <hip/hip_runtime.h>
#include <hip/hip_bf16.h>
#include <math.h>

// ---------------------------------------------------------------------------
// 5x conv4d(valid)+relu -> flatten -> dense(1280->33)+relu -> dense(33->2)
// -> softmax.  B=256.
//
// R8: R7 + one-time x fp32->bf16 pre-pad pass (cvt_x_pad) so conv1's staging
// becomes an identity uint4 copy (mode 2, CPR=ZPK/8=3) instead of per-element
// div/mod + f2bf (conv1 was VALUBusy 44.5%, 232us).  Gated on ws_size
// (155.7MB needed); falls back to R7-exact fp32 staging otherwise.
//  - conv1-3: banded-GEMM on v_mfma_f32_16x16x32_bf16 (R7-verified):
//    M=(ox,oy), N=co*16+oz, K=(ci,kx,ky)x(iz padded to ZPK), acc over kw.
//    B pre-packed in fragment order [kw][ks][nt][lane][8] (bf16 RNE).
//    A: one ds_read_b128 per fragment from z-padded LDS slab.
//    D: col=lane&15 (=oz), row=(lane>>4)*4+reg (=m).
//  - conv4/5 keep the R3 f16 dot2 path; dense1/2 unchanged.
// ---------------------------------------------------------------------------

#define BATCH 256
typedef _Float16 half_t;
typedef _Float16 h2_t  __attribute__((ext_vector_type(2)));
typedef short    bf16x8 __attribute__((ext_vector_type(8)));
typedef float    f32x4 __attribute__((ext_vector_type(4)));
typedef unsigned int   uint32;
typedef unsigned short ushort16;

__device__ __forceinline__ float dot2f(uint32 a, uint32 b, float c) {
    return __builtin_amdgcn_fdot2(__builtin_bit_cast(h2_t, a),
                                  __builtin_bit_cast(h2_t, b), c, false);
}

// f32 -> bf16 bits, round-to-nearest-even (finite inputs only)
__device__ __forceinline__ ushort16 f2bf(float f) {
    const uint32 u = __builtin_bit_cast(uint32, f);
    return (ushort16)((u + 0x7FFFu + ((u >> 16) & 1u)) >> 16);
}

// ---- x pre-pass: fp32 [256*18][324][18] -> bf16 [256*18][324][24], pads 0
__global__ void cvt_x_pad(const float* __restrict__ x,
                          ushort16* __restrict__ xp) {
    constexpr int CH  = 972;               // uint4 chunks per (b,iw) slice
    constexpr int NSL = BATCH * 18;
    const int c = blockIdx.x * blockDim.x + threadIdx.x;
    if (c >= NSL * CH) return;
    const int s   = c / CH;
    const int j   = c - s * CH;            // chunk within slice: row r=j/3
    const int r   = j / 3;
    const int g   = j - 3 * r;             // z-phase: elems 8g..8g+8 of 24
    const float* src = x + ((size_t)s * 324 + r) * 18 + 8 * g;
    uint32 w[4];
    if (g < 2) {                           // z 0..15 all valid
        #pragma unroll
        for (int q = 0; q < 4; ++q) {
            const float2 v = ((const float2*)src)[q];   // 8B-aligned
            w[q] = (uint32)f2bf(v.x) | ((uint32)f2bf(v.y) << 16);
        }
    } else {                               // z 16,17 valid; 18..23 pad
        const float2 v = *(const float2*)src;
        w[0] = (uint32)f2bf(v.x) | ((uint32)f2bf(v.y) << 16);
        w[1] = w[2] = w[3] = 0;
    }
    ((uint4*)xp)[c] = (uint4){w[0], w[1], w[2], w[3]};
}

// ---- B-matrix pre-pack: fragment order [kw][ks][nt][lane][8], bf16 -------
template <int CIN, int COUT, int ISZ, int OSZ, int ZPK, int KS>
__device__ void pack_mfma_one(const float* __restrict__ w,
                              ushort16* __restrict__ Bq, int gtid, int gstride) {
    constexpr int TOT = 4 * KS * COUT * 512;   // 512 bf16 per fragment
    for (int t = gtid; t < TOT; t += gstride) {
        const int h  = t & 7;
        const int l  = (t >> 3) & 63;
        const int f  = t >> 9;                 // (kw*KS+ks)*COUT + nt
        const int nt = f % COUT;
        const int ks = (f / COUT) % KS;
        const int kw = f / (COUT * KS);
        const int k  = ks * 32 + (l >> 4) * 8 + h;
        const int combo = k / ZPK;
        const int iz = k - combo * ZPK;
        const int ci = combo >> 4;             // combo = (ci*4+kx)*4+ky
        const int kx = (combo >> 2) & 3;
        const int ky = combo & 3;
        const int oz = l & 15;
        const int kz = iz - oz;
        ushort16 v = 0;
        if (oz < OSZ && kz >= 0 && kz < 4 && iz < ISZ)
            v = f2bf(w[((((nt * CIN + ci) * 4 + kw) * 4 + kx) * 4 + ky) * 4 + kz]);
        Bq[t] = v;
    }
}

__global__ void pack_weights_mfma(const float* __restrict__ w1,
                                  const float* __restrict__ w2,
                                  const float* __restrict__ w3,
                                  ushort16* __restrict__ Bq1,
                                  ushort16* __restrict__ Bq2,
                                  ushort16* __restrict__ Bq3) {
    const int gtid = blockIdx.x * blockDim.x + threadIdx.x;
    const int gs   = gridDim.x * blockDim.x;
    pack_mfma_one<1, 3, 18, 15, 24, 12>(w1, Bq1, gtid, gs);
    pack_mfma_one<3, 3, 15, 12, 16, 24>(w2, Bq2, gtid, gs);
    pack_mfma_one<3, 4, 12,  9, 16, 24>(w3, Bq3, gtid, gs);
}

// ---------------------------------------------------------------------------
// MFMA conv (bf16): one (b,ow) slab per block; waves split M-tiles; each wave
// accumulates all COUT n-tiles.
//  IN_MODE 0: fp32 natural rows stride ISZ (conv1 fallback)
//  IN_MODE 2: bf16 rows pre-padded to ZPK -> identity uint4 staging
//  OUTF16: emit f16 bits (conv3 -> conv4's dot2 path)
// ---------------------------------------------------------------------------
template <int CIN, int COUT, int ISZ, int OSZ, int ZPK, int KS,
          int MT_TOT, int NT, int IN_MODE, bool OUTF16>
__global__ __launch_bounds__(NT)
void conv4d_mfma(const void* __restrict__ in_v,
                 const ushort16* __restrict__ Bq,
                 const float* __restrict__ bias,
                 ushort16* __restrict__ out) {
    constexpr int K   = 4;
    constexpr int R2  = ISZ * ISZ;
    constexpr int NW  = NT / 64;
    constexpr int MT_PER = (MT_TOT + NW - 1) / NW;
    constexpr int SLAB = (CIN * R2 + 24) * ZPK;  // +24 rows OOB margin
    static_assert(CIN * 16 * ZPK == KS * 32, "K-dim bookkeeping");
    static_assert(ZPK % 8 == 0, "8-slice must not straddle combos");

    __shared__ ushort16 slab[SLAB];

    const int tid = threadIdx.x;
    const int l   = tid & 63;
    const int wv  = tid >> 6;
    const int b   = blockIdx.x / OSZ;
    const int ow  = blockIdx.x % OSZ;
    const int lg  = l >> 4;

    // NaN hardening: pads (ZPK>ISZ) and OOB margin must be finite.
    for (int t = tid; t < SLAB; t += NT) slab[t] = 0;

    // per-lane A-row base per owned M-tile
    int mbase[MT_PER];
    #pragma unroll
    for (int i = 0; i < MT_PER; ++i) {
        const int mt = wv + NW * i;
        const int m  = (mt < MT_TOT) ? (mt * 16 + (l & 15)) : 0;
        mbase[i] = (m / OSZ) * ISZ + (m % OSZ);
    }

    f32x4 acc[MT_PER][COUT];
    #pragma unroll
    for (int i = 0; i < MT_PER; ++i)
        #pragma unroll
        for (int nt = 0; nt < COUT; ++nt)
            acc[i][nt] = (f32x4){0.f, 0.f, 0.f, 0.f};

    for (int kw = 0; kw < K; ++kw) {
        __syncthreads();                       // readers of previous slab done
        const int iw = ow + kw;
        if constexpr (IN_MODE == 0) {
            // fp32 natural, CIN==1; float2 -> packed bf16 pairs
            const float* g = (const float*)in_v +
                ((size_t)b * ISZ + iw) * (size_t)(R2 * ISZ);
            for (int t = tid; t < (R2 * ISZ) / 2; t += NT) {
                const float2 v = ((const float2*)g)[t];
                const int e = 2 * t;
                const int r = e / ISZ, z = e % ISZ;    // ISZ even: no straddle
                const uint32 pv = (uint32)f2bf(v.x) | ((uint32)f2bf(v.y) << 16);
                *(uint32*)&slab[r * ZPK + z] = pv;
            }
        } else {
            constexpr int CPR = ZPK / 8;       // uint4 chunks per padded row
            constexpr int NCH = CIN * R2 * CPR;
            const ushort16* inp = (const ushort16*)in_v;
            for (int t = tid; t < NCH; t += NT) {
                const int ci  = t / (R2 * CPR);
                const int rem = t % (R2 * CPR);
                const uint4* g = (const uint4*)(inp +
                    ((size_t)(b * CIN + ci) * ISZ + iw) * (size_t)(R2 * ZPK));
                const uint4 v = g[rem];
                *(uint4*)&slab[(ci * R2) * ZPK + rem * 8] = v;
            }
        }
        __syncthreads();

        #pragma unroll 2
        for (int ks = 0; ks < KS; ++ks) {
            // weight fragments (L2-resident, coalesced 1KB per fragment)
            bf16x8 bq[COUT];
            const ushort16* bp = Bq + (size_t)((kw * KS + ks) * COUT) * 512 + l * 8;
            #pragma unroll
            for (int nt = 0; nt < COUT; ++nt)
                bq[nt] = *(const bf16x8*)(bp + nt * 512);
            // A fragment address parts (per-lane)
            const int k8    = ks * 32 + lg * 8;
            const int combo = k8 / ZPK;
            const int iz0   = k8 - combo * ZPK;
            const int ci    = combo >> 4;
            const int kx    = (combo >> 2) & 3;
            const int ky    = combo & 3;
            const int roff  = ci * R2 + kx * ISZ + ky;
            #pragma unroll
            for (int i = 0; i < MT_PER; ++i) {
                if (wv + NW * i < MT_TOT) {
                    const bf16x8 a =
                        *(const bf16x8*)&slab[(mbase[i] + roff) * ZPK + iz0];
                    #pragma unroll
                    for (int nt = 0; nt < COUT; ++nt)
                        acc[i][nt] = __builtin_amdgcn_mfma_f32_16x16x32_bf16(
                            a, bq[nt], acc[i][nt], 0, 0, 0);
                }
            }
        }
    }

    // ---- epilogue: D col = lane&15 (= oz), row = (lane>>4)*4 + reg (= m)
    const int oz = l & 15;
    #pragma unroll
    for (int i = 0; i < MT_PER; ++i) {
        const int mt = wv + NW * i;
        if (mt < MT_TOT) {
            #pragma unroll
            for (int nt = 0; nt < COUT; ++nt) {
                const float bv = bias[nt];
                #pragma unroll
                for (int r = 0; r < 4; ++r) {
                    const int m = mt * 16 + (l >> 4) * 4 + r;
                    if (m < OSZ * OSZ) {
                        const int ox = m / OSZ, oy = m % OSZ;
                        const float vv = fmaxf(acc[i][nt][r] + bv, 0.f);
                        ushort16 bits;
                        if constexpr (OUTF16) {
                            const half_t hv = (half_t)vv;
                            bits = __builtin_bit_cast(ushort16, hv);
                        } else {
                            bits = f2bf(vv);
                        }
                        out[(((((size_t)b * COUT + nt) * OSZ + ow) * OSZ + ox)
                             * OSZ + oy) * 16 + oz] = bits;
                    }
                }
            }
        }
    }
}

// ---------------------------------------------------------------------------
// R3 conv path (per-(co,ox,oy) lines, LDS weights, f16 dot2) — conv4/conv5.
// ---------------------------------------------------------------------------
template <int CIN, int COUT, int K, int ISZ, int OSZ,
          int IPG, int OPG, int ZP, int NT, bool INF32>
__global__ __launch_bounds__(NT)
void conv4d_relu_f16(const void* __restrict__ in_v,
                     const float* __restrict__ w,
                     const float* __restrict__ bias,
                     half_t* __restrict__ out) {
    constexpr int KP  = 4;
    constexpr int R2  = ISZ * ISZ;
    constexpr int WTOT = CIN * K * K * K * COUT * KP;
    constexpr int LINES = COUT * OSZ * OSZ;
    constexpr int NIT = (LINES + NT - 1) / NT;
    constexpr int RL  = OSZ + KP - 1;
    constexpr int RQ  = (RL + 7) / 8;
    constexpr int NW  = RQ * 4;
    constexpr int NODD = (OSZ + 2) / 2;

    static_assert(8 * RQ <= ZP, "row read overruns z-pad");
    static_assert(NODD + 1 <= NW, "perm source word out of range");

    __shared__ half_t sw[WTOT];
    __shared__ half_t slab[CIN * R2 * ZP];

    const int tid = threadIdx.x;
    const int b   = blockIdx.x / OSZ;
    const int ow  = blockIdx.x % OSZ;

    for (int t = tid; t < WTOT; t += NT) {
        const int kz = t % KP; int c = t / KP;
        const int co = c % COUT; c /= COUT;
        const int ky = c % K; c /= K;
        const int kx = c % K; c /= K;
        const int kw = c % K; const int ci = c / K;
        const float v = (kz < K)
            ? w[((((co * CIN + ci) * K + kw) * K + kx) * K + ky) * K + kz]
            : 0.0f;
        sw[t] = (half_t)v;
    }

    float acc[NIT][OSZ];
    #pragma unroll
    for (int it = 0; it < NIT; ++it) {
        const int line = tid + it * NT;
        const float bv = (line < LINES) ? bias[line % COUT] : 0.0f;
        #pragma unroll
        for (int oz = 0; oz < OSZ; ++oz) acc[it][oz] = bv;
    }

    for (int kw = 0; kw < K; ++kw) {
        __syncthreads();
        const int iw = ow + kw;
        if constexpr (INF32) {
            const float* g = (const float*)in_v + ((size_t)b * ISZ + iw) * (size_t)(R2 * ISZ);
            for (int t = tid; t < R2 * ISZ; t += NT) {
                const int r = t / ISZ, z = t % ISZ;
                slab[r * ZP + z] = (half_t)g[t];
            }
        } else {
            constexpr int CPR = IPG / 8;
            constexpr int NCH = CIN * R2 * CPR;
            const half_t* inp = (const half_t*)in_v;
            for (int t = tid; t < NCH; t += NT) {
                const int ci  = t / (R2 * CPR);
                const int rem = t % (R2 * CPR);
                const int r = rem / CPR, c = rem % CPR;
                const uint4* g = (const uint4*)(inp +
                    ((size_t)(b * CIN + ci) * ISZ + iw) * (size_t)(R2 * IPG));
                const uint4 v = g[rem];
                *(uint4*)&slab[(ci * R2 + r) * ZP + 8 * c] = v;
            }
        }
        __syncthreads();

        #pragma unroll
        for (int it = 0; it < NIT; ++it) {
            const int line = tid + it * NT;
            if (line >= LINES) continue;
            const int co = line % COUT;
            const int xy = line / COUT;
            const int ox = xy / OSZ;
            const int oy = xy % OSZ;
            #pragma unroll 1
            for (int ci = 0; ci < CIN; ++ci) {
                #pragma unroll 1
                for (int kx = 0; kx < K; ++kx) {
                    #pragma unroll
                    for (int ky = 0; ky < K; ++ky) {
                        const half_t* rp = &slab[((ci * ISZ + ox + kx) * ISZ + oy + ky) * ZP];
                        uint32 wd[NW];
                        #pragma unroll
                        for (int q = 0; q < RQ; ++q) {
                            const uint4 v = ((const uint4*)rp)[q];
                            wd[4*q+0] = v.x; wd[4*q+1] = v.y;
                            wd[4*q+2] = v.z; wd[4*q+3] = v.w;
                        }
                        uint32 od[NODD];
                        #pragma unroll
                        for (int i = 0; i < NODD; ++i)
                            od[i] = __builtin_amdgcn_perm(wd[i + 1], wd[i], 0x05040302u);
                        const int wb = ((((ci * K + kw) * K + kx) * K + ky) * COUT + co) * KP;
                        const uint2 wv = *(const uint2*)&sw[wb];
                        #pragma unroll
                        for (int oz = 0; oz < OSZ; ++oz) {
                            const int s1 = oz + 2;
                            const uint32 p0 = (oz & 1) ? od[oz >> 1] : wd[oz >> 1];
                            const uint32 p1 = (s1 & 1) ? od[s1 >> 1] : wd[s1 >> 1];
                            acc[it][oz] = dot2f(p0, wv.x, dot2f(p1, wv.y, acc[it][oz]));
                        }
                    }
                }
            }
        }
    }

    #pragma unroll
    for (int it = 0; it < NIT; ++it) {
        const int line = tid + it * NT;
        if (line >= LINES) continue;
        const int co = line % COUT;
        const int xy = line / COUT;
        const int ox = xy / OSZ;
        const int oy = xy % OSZ;
        half_t* op = out + (((((size_t)b * COUT + co) * OSZ + ow) * OSZ + ox) * OSZ + oy) * OPG;
        #pragma unroll
        for (int p = 0; p < OSZ / 2; ++p) {
            h2_t pv = { (half_t)fmaxf(acc[it][2*p],     0.0f),
                        (half_t)fmaxf(acc[it][2*p + 1], 0.0f) };
            ((uint32*)op)[p] = __builtin_bit_cast(uint32, pv);
        }
        if constexpr (OSZ & 1)
            op[OSZ - 1] = (half_t)fmaxf(acc[it][OSZ - 1], 0.0f);
    }
}

// dense1: out[b,j] = relu(sum_k h[b,k]*w[j,k] + bias[j]); h f16 [256,1280]
__global__ void dense1_relu_f16(const half_t* __restrict__ h,
                                const float* __restrict__ w,
                                const float* __restrict__ bias,
                                float* __restrict__ out) {
    int idx = blockIdx.x * blockDim.x + threadIdx.x;
    if (idx >= BATCH * 33) return;
    const int j = idx % 33;
    const int i = idx / 33;
    const half_t* hr = h + (size_t)i * 1280;
    const float*  wr = w + (size_t)j * 1280;
    float a0 = bias[j], a1 = 0.f, a2 = 0.f, a3 = 0.f;
    for (int k = 0; k < 1280; k += 4) {
        a0 = fmaf((float)hr[k + 0], wr[k + 0], a0);
        a1 = fmaf((float)hr[k + 1], wr[k + 1], a1);
        a2 = fmaf((float)hr[k + 2], wr[k + 2], a2);
        a3 = fmaf((float)hr[k + 3], wr[k + 3], a3);
    }
    out[idx] = fmaxf((a0 + a1) + (a2 + a3), 0.0f);
}

// dense2 + softmax over 2 classes. h:[256,33] fp32, w:[2,33], out:[256,2]
__global__ void dense2_softmax(const float* __restrict__ h,
                               const float* __restrict__ w,
                               const float* __restrict__ bias,
                               float* __restrict__ out) {
    int i = blockIdx.x * blockDim.x + threadIdx.x;
    if (i >= BATCH) return;
    const float* hr = h + (size_t)i * 33;
    float a0 = bias[0], a1 = bias[1];
    for (int k = 0; k < 33; ++k) {
        a0 = fmaf(hr[k], w[k], a0);
        a1 = fmaf(hr[k], w[33 + k], a1);
    }
    const float m = fmaxf(a0, a1);
    const float e0 = expf(a0 - m);
    const float e1 = expf(a1 - m);
    const float s = e0 + e1;
    out[i * 2 + 0] = e0 / s;
    out[i * 2 + 1] = e1 / s;
}

extern "C" void kernel_launch(void* const* d_in, const int* in_sizes, int n_in,
                              void* d_out, int out_size, void* d_ws, size_t ws_size,
                              hipStream_t stream) {
    const float* x   = (const float*)d_in[0];
    const float* w1  = (const float*)d_in[1];
    const float* b1  = (const float*)d_in[2];
    const float* w2  = (const float*)d_in[3];
    const float* b2  = (const float*)d_in[4];
    const float* w3  = (const float*)d_in[5];
    const float* b3  = (const float*)d_in[6];
    const float* w4  = (const float*)d_in[7];
    const float* b4  = (const float*)d_in[8];
    const float* w5  = (const float*)d_in[9];
    const float* b5  = (const float*)d_in[10];
    const float* dw1 = (const float*)d_in[11];
    const float* db1 = (const float*)d_in[12];
    const float* dw2 = (const float*)d_in[13];
    const float* db2 = (const float*)d_in[14];

    // Workspace (16-bit units). Region A at 0, region B at 42M (84 MB).
    //  A: h1 bf16 41.472M / h3(f16) / h5(f16); Bq1..Bq3 at A+41.5M
    //  B: xp bf16 35.83M (dead after conv1) / h2 bf16 21.23M / h4(f16)
    //     / h6(fp32 at +8M ushort16-units)
    ushort16* wsA = (ushort16*)d_ws;
    ushort16* wsB = wsA + 42000000;

    ushort16* h1 = wsA;               // bf16, padded z=16
    ushort16* xp = wsB;               // bf16, padded z=24 (35,831,808)
    ushort16* h2 = wsB;               // bf16, padded z=16 (after xp dead)
    ushort16* h3 = wsA;               // f16 bits, padded z=16
    half_t*   h4 = (half_t*)wsB;      // f16, padded z=8
    half_t*   h5 = (half_t*)wsA;      // f16, natural [256][1280]
    float*    h6 = (float*)(wsB + 8000000);
    ushort16* Bq1 = wsA + 41500000;   // 4*12*3*512 = 73,728
    ushort16* Bq2 = wsA + 41600000;   // 4*24*3*512 = 147,456
    ushort16* Bq3 = wsA + 41760000;   // 4*24*4*512 = 196,608
    float* outp = (float*)d_out;

    // primary layout needs (42,000,000 + 35,831,808) * 2 bytes
    const bool big_ws = ws_size >= (size_t)155663616ull;

    // weight fragment pre-pack for conv1-3
    hipLaunchKernelGGL(pack_weights_mfma, dim3(64), dim3(256), 0, stream,
                       w1, w2, w3, Bq1, Bq2, Bq3);

    if (big_ws) {
        // x fp32 -> bf16 pre-padded [b][iw][324][24]
        constexpr int NCH = BATCH * 18 * 972;
        hipLaunchKernelGGL(cvt_x_pad, dim3((NCH + 255) / 256), dim3(256),
                           0, stream, x, xp);
        // conv1 from xp: identity-copy staging (IN_MODE 2)
        hipLaunchKernelGGL((conv4d_mfma<1, 3, 18, 15, 24, 12, 15, 256, 2, false>),
                           dim3(BATCH * 15), dim3(256), 0, stream, xp, Bq1, b1, h1);
    } else {
        // fallback: R7-exact fp32 staging (IN_MODE 0)
        hipLaunchKernelGGL((conv4d_mfma<1, 3, 18, 15, 24, 12, 15, 256, 0, false>),
                           dim3(BATCH * 15), dim3(256), 0, stream, x, Bq1, b1, h1);
    }
    // conv2: h1 -> h2 (bf16).  M=144 (9 Mt), ZPK=16, KS=24.
    hipLaunchKernelGGL((conv4d_mfma<3, 3, 15, 12, 16, 24, 9, 256, 2, false>),
                       dim3(BATCH * 12), dim3(256), 0, stream, h1, Bq2, b2, h2);
    // conv3: h2 -> h3 (f16 out for conv4).  M=81 (6 Mt), ZPK=16, KS=24.
    hipLaunchKernelGGL((conv4d_mfma<3, 4, 12, 9, 16, 24, 6, 256, 2, true>),
                       dim3(BATCH * 9), dim3(256), 0, stream, h2, Bq3, b3, h3);
    // conv4: h3 -> h4;  R3 f16 dot2 path
    hipLaunchKernelGGL((conv4d_relu_f16<4, 5, 4, 9, 6, 16, 8, 24, 192, false>),
                       dim3(BATCH * 6), dim3(192), 0, stream, h3, w4, b4, h4);
    // conv5: h4 -> h5 (natural, z=4);  R3 f16 dot2 path
    hipLaunchKernelGGL((conv4d_relu_f16<5, 5, 3, 6, 4, 8, 4, 8, 128, false>),
                       dim3(BATCH * 4), dim3(128), 0, stream, h4, w5, b5, h5);
    {   // dense1
        dim3 grid((BATCH * 33 + 255) / 256);
        hipLaunchKernelGGL(dense1_relu_f16, grid, dim3(256), 0, stream, h5, dw1, db1, h6);
    }
    {   // dense2 + softmax
        hipLaunchKernelGGL(dense2_softmax, dim3(1), dim3(256), 0, stream,
                           h6, dw2, db2, outp);
    }
}